// Round 14
// baseline (703.754 us; speedup 1.0000x reference)
//
#include <hip/hip_runtime.h>

// GridDVAE: 5-stage attention pooling + VQ, MI355X gfx950.
// R14: occupancy experiment — gemm_m (m97-family: 128^2 tile, BK=32, 4 waves,
// 32KB dbuf LDS, launch_bounds(256,3) => 3 blocks/CU = 12 waves/CU, counted
// vmcnt(4)) replaces gemm_c/gemm_s for all b128>=192 shapes. gemm_t (64^2,
// 4 blk/CU) keeps the grid-starved shapes. Everything else = R13.

#define MB (1024ull * 1024ull)

typedef unsigned short u16;
typedef __attribute__((ext_vector_type(4))) float f32x4;
typedef __bf16 bf16x8 __attribute__((ext_vector_type(8)));

__device__ __forceinline__ u16 f2bf(float f) {
  unsigned u = __float_as_uint(f);
  unsigned r = u + 0x7FFFu + ((u >> 16) & 1u);   // RNE
  return (u16)(r >> 16);
}
__device__ __forceinline__ float bf2f(u16 h) {
  return __uint_as_float(((unsigned)h) << 16);
}

typedef __attribute__((address_space(1))) const void GASV;
typedef __attribute__((address_space(3))) void LASV;
__device__ __forceinline__ void async16(const void* g, void* l) {
  __builtin_amdgcn_global_load_lds((GASV*)g, (LASV*)l, 16, 0, 0);
}

__device__ __forceinline__ int xcd_swz(int bid, int nwg) {
  const int q8 = nwg >> 3, r8 = nwg & 7;
  const int xcd = bid & 7, idx = bid >> 3;
  return (xcd < r8 ? xcd * (q8 + 1) : r8 * (q8 + 1) + (xcd - r8) * q8) + idx;
}

// ---------------------------------------------------------------------------
// gemm_m: 128x128/BK=32, 4 waves (2x2), 256 thr, 32 KiB LDS dbuf,
// launch_bounds(256,3) -> 3 blocks/CU (12 waves/CU). Counted vmcnt(4).
// Per K-tile: 4 async16/thread stage, 8 ds_read_b128, 16 MFMA.
// LDS idx: buf*8192 + mat*4096 + row*32 + slot*8 (u16). Swizzle slot^((row>>1)&3).
// MODE 0: f32 C. 1: bf16 C.
// ---------------------------------------------------------------------------
template<int MODE>
__global__ __launch_bounds__(256, 3)
void gemm_m(const u16* __restrict__ A, const u16* __restrict__ B,
            float* __restrict__ Cf, u16* __restrict__ Cb,
            int M, int N, int KLEN, int ld,
            long long sA, long long sB, long long sC, int ldc, float alpha,
            int nxt, int nyt)
{
  __shared__ u16 lds[16384];   // 32 KiB
  const int tid  = threadIdx.x;
  const int lane = tid & 63;
  const int w    = tid >> 6;       // 0..3
  const int wr   = w >> 1, wc = w & 1;

  const int wg = xcd_swz((int)blockIdx.x, (int)gridDim.x);
  const int bx = wg % nxt;
  const int by = (wg / nxt) % nyt;
  const int bz = wg / (nxt * nyt);

  const int m0 = by * 128, n0 = bx * 128;
  const u16* Ab = A + (size_t)bz * sA;
  const u16* Bb = B + (size_t)bz * sB;
  const int NT = KLEN >> 5;        // BK = 32

  f32x4 acc[4][4] = {};

  // staging: 4 async16/thread; mat m, half j: row r = j*64 + (tid>>2),
  // src slot sg = (tid&3)^((tid>>3)&3) (matches read swizzle; j,w drop out).
  const int Rq  = tid >> 2;                  // 0..63
  const int sgs = (tid & 3) ^ ((tid >> 3) & 3);
  int ra0 = m0 + Rq;       ra0 = ra0 < M - 1 ? ra0 : M - 1;
  int ra1 = m0 + 64 + Rq;  ra1 = ra1 < M - 1 ? ra1 : M - 1;
  int rb0 = n0 + Rq;       rb0 = rb0 < N - 1 ? rb0 : N - 1;
  int rb1 = n0 + 64 + Rq;  rb1 = rb1 < N - 1 ? rb1 : N - 1;
  const u16* gA0 = Ab + (size_t)ra0 * ld + (sgs << 3);
  const u16* gA1 = Ab + (size_t)ra1 * ld + (sgs << 3);
  const u16* gB0 = Bb + (size_t)rb0 * ld + (sgs << 3);
  const u16* gB1 = Bb + (size_t)rb1 * ld + (sgs << 3);
  const int ldst = (w << 4) * 32;            // wave dst base within 64-row half

  auto stage = [&](int t, int buf) {
    const int kc = t << 5;
    u16* d = &lds[(buf << 13) + ldst];
    async16(gA0 + kc, d);
    async16(gA1 + kc, d + 2048);             // rows 64-127 of A
    async16(gB0 + kc, d + 4096);             // B half 0
    async16(gB1 + kc, d + 6144);             // B rows 64-127
  };

  // reads: per-thread const bases, imm offsets (f*512)
  const int rsel = lane & 15;
  const int ksub = lane >> 4;                // 0..3
  const int sw   = ksub ^ ((rsel >> 1) & 3);
  const u16* ldsA = &lds[(wr * 64 + rsel) * 32 + sw * 8];
  const u16* ldsB = &lds[4096 + (wc * 64 + rsel) * 32 + sw * 8];

  stage(0, 0);
  if (NT > 1) stage(1, 1);
  for (int t = 0; t < NT; ++t) {
    const int buf = t & 1;
    if (t + 1 < NT) asm volatile("s_waitcnt vmcnt(4)" ::: "memory");
    else            asm volatile("s_waitcnt vmcnt(0)" ::: "memory");
    __builtin_amdgcn_s_barrier();
    bf16x8 a[4], b[4];
#pragma unroll
    for (int f = 0; f < 4; ++f) {
      a[f] = *(const bf16x8*)&ldsA[buf * 8192 + f * 512];
      b[f] = *(const bf16x8*)&ldsB[buf * 8192 + f * 512];
    }
    __builtin_amdgcn_s_setprio(1);
#pragma unroll
    for (int mi = 0; mi < 4; ++mi)
#pragma unroll
      for (int ni = 0; ni < 4; ++ni)
        acc[mi][ni] = __builtin_amdgcn_mfma_f32_16x16x32_bf16(
            a[mi], b[ni], acc[mi][ni], 0, 0, 0);
    __builtin_amdgcn_s_setprio(0);
    __builtin_amdgcn_s_barrier();
    if (t + 2 < NT) stage(t + 2, buf);
  }

  // epilogue: C row = (lane>>4)*4 + i, col = lane&15 (m89-verified layout)
#pragma unroll
  for (int mi = 0; mi < 4; ++mi)
#pragma unroll
    for (int ni = 0; ni < 4; ++ni)
#pragma unroll
      for (int i = 0; i < 4; ++i) {
        const int row = m0 + wr * 64 + mi * 16 + ((lane >> 4) << 2) + i;
        const int col = n0 + wc * 64 + ni * 16 + rsel;
        if (row < M && col < N) {
          const float v = acc[mi][ni][i] * alpha;
          const size_t off = (size_t)bz * sC + (size_t)row * ldc + col;
          if (MODE == 0) Cf[off] = v;
          else           Cb[off] = f2bf(v);
        }
      }
}

// ---------------------------------------------------------------------------
// gemm_t: 64x64/BK=64, 4 waves (2x2, per-wave 32x32), 256 thr, 32 KiB LDS
// dbuf -> ~4-5 blocks/CU. For grid-starved GEMMs.
// ---------------------------------------------------------------------------
template<int MODE>
__global__ __launch_bounds__(256, 4)
void gemm_t(const u16* __restrict__ A, const u16* __restrict__ B,
            float* __restrict__ Cf, u16* __restrict__ Cb,
            int M, int N, int KLEN, int ld,
            long long sA, long long sB, long long sC, int ldc, float alpha,
            int nxt, int nyt)
{
  __shared__ u16 lds[16384];   // [buf<<13 | mat<<12 | row*64 + slot*8]
  const int tid  = threadIdx.x;
  const int lane = tid & 63;
  const int w    = tid >> 6;       // 0..3
  const int wr   = w >> 1, wc = w & 1;

  const int wg = xcd_swz((int)blockIdx.x, (int)gridDim.x);
  const int bx = wg % nxt;
  const int by = (wg / nxt) % nyt;
  const int bz = wg / (nxt * nyt);

  const int m0 = by * 64, n0 = bx * 64;
  const u16* Ab = A + (size_t)bz * sA;
  const u16* Bb = B + (size_t)bz * sB;
  const int NT = KLEN >> 6;

  f32x4 acc[2][2] = {};

  const int Rl  = tid >> 3;                  // 0..31
  const int sgs = (tid & 7) ^ (Rl & 7);      // involution src slot

  auto stage = [&](int t, int buf) {
    const int kc = t << 6;
#pragma unroll
    for (int j = 0; j < 4; ++j) {
      const int mat = j >> 1, rh = j & 1;
      int rg = (mat ? n0 : m0) + rh * 32 + Rl;
      const int lim = (mat ? N : M) - 1;
      rg = rg < lim ? rg : lim;
      const u16* src = (mat ? Bb : Ab) + (size_t)rg * ld + kc + (sgs << 3);
      async16(src, &lds[(buf << 13) + (mat << 12) + (rh * 32 + w * 8) * 64]);
    }
  };

  const int rsel = lane & 15, ksub = lane >> 4;
  const int e  = rsel & 7;
  const int s0 = ((e >> 2) << 2) | (ksub ^ (e & 3));
  const int s1 = s0 ^ 4;
  const u16* lA0 = &lds[(wr * 32 + rsel) * 64 + s0 * 8];
  const u16* lA1 = &lds[(wr * 32 + rsel) * 64 + s1 * 8];
  const u16* lB0 = &lds[4096 + (wc * 32 + rsel) * 64 + s0 * 8];
  const u16* lB1 = &lds[4096 + (wc * 32 + rsel) * 64 + s1 * 8];

  stage(0, 0);
  for (int t = 0; t < NT; ++t) {
    const int buf = t & 1;
    if (t + 1 < NT) {
      stage(t + 1, buf ^ 1);
      asm volatile("s_waitcnt vmcnt(4)" ::: "memory");
    } else {
      asm volatile("s_waitcnt vmcnt(0)" ::: "memory");
    }
    __builtin_amdgcn_s_barrier();
    bf16x8 af[2][2], bg[2][2];
#pragma unroll
    for (int f = 0; f < 2; ++f) {
      af[f][0] = *(const bf16x8*)&lA0[buf * 8192 + f * 1024];
      af[f][1] = *(const bf16x8*)&lA1[buf * 8192 + f * 1024];
      bg[f][0] = *(const bf16x8*)&lB0[buf * 8192 + f * 1024];
      bg[f][1] = *(const bf16x8*)&lB1[buf * 8192 + f * 1024];
    }
    __builtin_amdgcn_s_setprio(1);
#pragma unroll
    for (int mi = 0; mi < 2; ++mi)
#pragma unroll
      for (int ni = 0; ni < 2; ++ni)
#pragma unroll
        for (int kh = 0; kh < 2; ++kh)
          acc[mi][ni] = __builtin_amdgcn_mfma_f32_16x16x32_bf16(
              af[mi][kh], bg[ni][kh], acc[mi][ni], 0, 0, 0);
    __builtin_amdgcn_s_setprio(0);
    __builtin_amdgcn_s_barrier();
  }

#pragma unroll
  for (int mi = 0; mi < 2; ++mi)
#pragma unroll
    for (int ni = 0; ni < 2; ++ni)
#pragma unroll
      for (int i = 0; i < 4; ++i) {
        const int row = m0 + wr * 32 + mi * 16 + ((lane >> 4) << 2) + i;
        const int col = n0 + wc * 32 + ni * 16 + rsel;
        if (row < M && col < N) {
          const float v = acc[mi][ni][i] * alpha;
          const size_t off = (size_t)bz * sC + (size_t)row * ldc + col;
          if (MODE == 0) Cf[off] = v;
          else           Cb[off] = f2bf(v);
        }
      }
}

// single-launch cast of qry, wq, wk, wv, cb (f32 -> bf16)
__global__ void multicast_k(const float* __restrict__ q, const float* __restrict__ wqp,
                            const float* __restrict__ wkp, const float* __restrict__ wvp,
                            const float* __restrict__ cbp,
                            u16* __restrict__ dq, u16* __restrict__ dwq,
                            u16* __restrict__ dwk, u16* __restrict__ dwv,
                            u16* __restrict__ dcb)
{
  long long i = (long long)blockIdx.x * 256 + threadIdx.x;
  const long long stride = (long long)gridDim.x * 256;
  for (; i < 5373952ll; i += stride) {
    const float* src; u16* dst; long long j;
    if (i < 1310720)      { src = q;   dst = dq;  j = i; }
    else if (i < 2621440) { src = wqp; dst = dwq; j = i - 1310720; }
    else if (i < 3932160) { src = wkp; dst = dwk; j = i - 2621440; }
    else if (i < 5242880) { src = wvp; dst = dwv; j = i - 3932160; }
    else                  { src = cbp; dst = dcb; j = i - 5242880; }
    const float4 v = *(const float4*)&src[j << 2];
    *(ushort4*)&dst[j << 2] = make_ushort4(f2bf(v.x), f2bf(v.y), f2bf(v.z), f2bf(v.w));
  }
}

// f32 [z][1024][1024] -> bf16 straight + bf16 transposed (fused)
__global__ __launch_bounds__(256)
void cast_trans_k(const float* __restrict__ in, u16* __restrict__ h,
                  u16* __restrict__ ht)
{
  __shared__ float t[32][33];
  const int z = blockIdx.z;
  const float* src = in + (size_t)z * 1048576;
  u16* dh = h  + (size_t)z * 1048576;
  u16* dt = ht + (size_t)z * 1048576;
  const int x0 = blockIdx.x * 32, y0 = blockIdx.y * 32;
  const int tx = threadIdx.x, ty = threadIdx.y;
#pragma unroll
  for (int k = 0; k < 4; ++k) {
    const float v = src[(size_t)(y0 + ty + 8 * k) * 1024 + (x0 + tx)];
    t[ty + 8 * k][tx] = v;
    dh[(size_t)(y0 + ty + 8 * k) * 1024 + (x0 + tx)] = f2bf(v);
  }
  __syncthreads();
#pragma unroll
  for (int k = 0; k < 4; ++k)
    dt[(size_t)(x0 + ty + 8 * k) * 1024 + (y0 + tx)] = f2bf(t[tx][ty + 8 * k]);
}

// f32 [z][1024][1024] -> bf16 transposed only
__global__ __launch_bounds__(256)
void transpose_cast_k(const float* __restrict__ in, u16* __restrict__ out)
{
  __shared__ float t[32][33];
  const int z = blockIdx.z;
  const float* src = in + (size_t)z * 1048576;
  u16* dst = out + (size_t)z * 1048576;
  const int x0 = blockIdx.x * 32, y0 = blockIdx.y * 32;
  const int tx = threadIdx.x, ty = threadIdx.y;
#pragma unroll
  for (int k = 0; k < 4; ++k)
    t[ty + 8 * k][tx] = src[(size_t)(y0 + ty + 8 * k) * 1024 + (x0 + tx)];
  __syncthreads();
#pragma unroll
  for (int k = 0; k < 4; ++k)
    dst[(size_t)(x0 + ty + 8 * k) * 1024 + (y0 + tx)] = f2bf(t[tx][ty + 8 * k]);
}

// bf16 [z][R][1024] -> [z][1024][R]
__global__ __launch_bounds__(256)
void transpose_u16_k(const u16* __restrict__ in, u16* __restrict__ out, int R)
{
  __shared__ u16 t[32][33];
  const size_t zi = (size_t)blockIdx.z * R * 1024;
  const size_t zo = (size_t)blockIdx.z * 1024 * R;
  const int x0 = blockIdx.x * 32, y0 = blockIdx.y * 32;
  const int tx = threadIdx.x, ty = threadIdx.y;
#pragma unroll
  for (int k = 0; k < 4; ++k)
    t[ty + 8 * k][tx] = in[zi + (size_t)(y0 + ty + 8 * k) * 1024 + (x0 + tx)];
  __syncthreads();
#pragma unroll
  for (int k = 0; k < 4; ++k)
    out[zo + (size_t)(x0 + ty + 8 * k) * R + (y0 + tx)] = t[tx][ty + 8 * k];
}

// row softmax (len S<=1024): bf16 logits in -> bf16 attn out
__global__ __launch_bounds__(256)
void softmax_b(const u16* __restrict__ lg, u16* __restrict__ at, int S)
{
  const size_t row = blockIdx.x;
  const u16* src = lg + row * S;
  const int tid = threadIdx.x;
  float v[4];
  float mx = -3.402823466e38f;
#pragma unroll
  for (int c = 0; c < 4; ++c) {
    const int j = tid + c * 256;
    v[c] = (j < S) ? bf2f(src[j]) : -3.402823466e38f;
    mx = fmaxf(mx, v[c]);
  }
#pragma unroll
  for (int o = 32; o > 0; o >>= 1) mx = fmaxf(mx, __shfl_xor(mx, o));
  __shared__ float rmx[4];
  if ((tid & 63) == 0) rmx[tid >> 6] = mx;
  __syncthreads();
  mx = fmaxf(fmaxf(rmx[0], rmx[1]), fmaxf(rmx[2], rmx[3]));
  float sum = 0.f;
#pragma unroll
  for (int c = 0; c < 4; ++c) { v[c] = expf(v[c] - mx); sum += v[c]; }
#pragma unroll
  for (int o = 32; o > 0; o >>= 1) sum += __shfl_xor(sum, o);
  __shared__ float rsm[4];
  if ((tid & 63) == 0) rsm[tid >> 6] = sum;
  __syncthreads();
  sum = rsm[0] + rsm[1] + rsm[2] + rsm[3];
  const float inv = 1.0f / sum;
  u16* dst = at + row * S;
#pragma unroll
  for (int c = 0; c < 4; ++c) {
    const int j = tid + c * 256;
    if (j < S) dst[j] = f2bf(v[c] * inv);
  }
}

// per-code squared norm
__global__ __launch_bounds__(256)
void cnorm_kernel(const float* __restrict__ cb, float* __restrict__ cn)
{
  const int c = blockIdx.x;
  const float4 v = ((const float4*)(cb + (size_t)c * 1024))[threadIdx.x];
  float s = v.x * v.x + v.y * v.y + v.z * v.z + v.w * v.w;
#pragma unroll
  for (int o = 32; o > 0; o >>= 1) s += __shfl_xor(s, o);
  __shared__ float r4[4];
  if ((threadIdx.x & 63) == 0) r4[threadIdx.x >> 6] = s;
  __syncthreads();
  if (threadIdx.x == 0) cn[c] = r4[0] + r4[1] + r4[2] + r4[3];
}

// per latent: argmin_c (cn[c] - 2*dot[lat,c]), tie -> lower c; gather code row
__global__ __launch_bounds__(256)
void argmin_gather_k(const float* __restrict__ dot, const float* __restrict__ cn,
                     const float* __restrict__ cb, float* __restrict__ out)
{
  const size_t lat = blockIdx.x;
  const int tid = threadIdx.x;
  const float* dr = dot + lat * 512;
  float best = 3.402823466e38f;
  int bi = 0;
#pragma unroll
  for (int cc = 0; cc < 2; ++cc) {
    const int c = tid + cc * 256;
    const float sc = cn[c] - 2.0f * dr[c];
    if (sc < best || (sc == best && c < bi)) { best = sc; bi = c; }
  }
  __shared__ float rb[256];
  __shared__ int   ri[256];
  rb[tid] = best; ri[tid] = bi;
  __syncthreads();
  for (int s = 128; s > 0; s >>= 1) {
    if (tid < s) {
      const float ob = rb[tid + s];
      const int oi = ri[tid + s];
      if (ob < rb[tid] || (ob == rb[tid] && oi < ri[tid])) { rb[tid] = ob; ri[tid] = oi; }
    }
    __syncthreads();
  }
  const int sel = ri[0];
  ((float4*)(out + lat * 1024))[tid] = ((const float4*)(cb + (size_t)sel * 1024))[tid];
}

__global__ void fill_kernel(float* p, float v, int n) {
  const int i = blockIdx.x * 256 + threadIdx.x;
  if (i < n) p[i] = v;
}

// ---------------------------------------------------------------------------
// mode: 0 f32, 1 bf16
static void gX(hipStream_t st, int mode,
               const u16* A, const u16* B, float* Cf, u16* Cb,
               int M, int N, int KLEN, int ld,
               long long sA, long long sB, long long sC, int ldc,
               int batch, float alpha)
{
  const int b128 = ((M + 127) / 128) * ((N + 127) / 128) * batch;
  if (b128 >= 192 && M >= 128 && (KLEN & 63) == 0) {
    const int nxt = (N + 127) / 128, nyt = (M + 127) / 128;
    dim3 grid(nxt * nyt * batch), blk(256);
    if (mode == 0)
      gemm_m<0><<<grid, blk, 0, st>>>(A, B, Cf, Cb, M, N, KLEN, ld, sA, sB, sC, ldc, alpha, nxt, nyt);
    else
      gemm_m<1><<<grid, blk, 0, st>>>(A, B, Cf, Cb, M, N, KLEN, ld, sA, sB, sC, ldc, alpha, nxt, nyt);
  } else {
    const int nxt = (N + 63) / 64, nyt = (M + 63) / 64;
    dim3 grid(nxt * nyt * batch), blk(256);
    if (mode == 0)
      gemm_t<0><<<grid, blk, 0, st>>>(A, B, Cf, Cb, M, N, KLEN, ld, sA, sB, sC, ldc, alpha, nxt, nyt);
    else
      gemm_t<1><<<grid, blk, 0, st>>>(A, B, Cf, Cb, M, N, KLEN, ld, sA, sB, sC, ldc, alpha, nxt, nyt);
  }
}

extern "C" void kernel_launch(void* const* d_in, const int* in_sizes, int n_in,
                              void* d_out, int out_size, void* d_ws, size_t ws_size,
                              hipStream_t stream)
{
  const float* x   = (const float*)d_in[0];
  const float* qry = (const float*)d_in[1];
  const float* wq  = (const float*)d_in[2];
  const float* wk  = (const float*)d_in[3];
  const float* wv  = (const float*)d_in[4];
  const float* wo  = (const float*)d_in[5];
  const float* cb  = (const float*)d_in[6];
  float* out = (float*)d_out;

  const size_t NEED = 312 * MB;
  if (ws_size < NEED) {
    fill_kernel<<<(out_size + 255) / 256, 256, 0, stream>>>(out, (float)ws_size, out_size);
    return;
  }
  char* ws = (char*)d_ws;
  const long long W = 1048576;  // 1024*1024 elements
  // persistent
  u16*  QKb   = (u16*)(ws + 0 * MB);    // [5W] QK_i = Q·wq·wk^T
  u16*  WqkTb = (u16*)(ws + 10 * MB);   // [5W] z10 C batches 0-4
  u16*  WVOb  = (u16*)(ws + 20 * MB);   // [5W] z10 C batches 5-9: (Wv·Wo)^T
  u16*  CBb   = (u16*)(ws + 30 * MB);   // [512,1024]
  float* CN   = (float*)(ws + 31 * MB); // [512]
  u16*  QKP   = (u16*)(ws + 32 * MB);   // [4W] QK'_i
  u16*  WCb   = (u16*)(ws + 40 * MB);   // [4W] Wc1..Wc4
  u16*  WC5   = (u16*)(ws + 48 * MB);   // [W]
  u16*  CBW   = (u16*)(ws + 50 * MB);   // G = NT(CB, Wc5)
  float* DOT  = (float*)(ws + 51 * MB); // [2048,512]
  // transient
  u16*  U    = (u16*)(ws + 56 * MB);    // u_i [32][S,1024]
  u16*  UT   = (u16*)(ws + 120 * MB);   // u^T [32][1024,S]
  u16*  ATb  = (u16*)(ws + 184 * MB);   // attn [32][KO,S]
  u16*  LOG  = (u16*)(ws + 248 * MB);   // logits bf16
  // setup transients (overlay U/UT, dead before cast_trans)
  u16*  QSb  = (u16*)(ws + 56 * MB);    // queries [5W]
  u16*  WQb  = (u16*)(ws + 66 * MB);    // B-group batches 0-4
  u16*  WVb  = (u16*)(ws + 76 * MB);    // B-group batches 5-9
  u16*  WKb  = (u16*)(ws + 86 * MB);    // A-group batches 0-4
  u16*  WOTb = (u16*)(ws + 96 * MB);    // A-group batches 5-9

  const int S_in[5]  = {1024, 1024, 512, 256, 128};
  const int K_out[5] = {1024, 512, 256, 128, 64};

  // ---- setup ----
  multicast_k<<<2048, 256, 0, stream>>>(qry, wq, wk, wv, cb,
                                        QSb, WQb, WKb, WVb, CBb);
  dim3 tb(32, 8), tg5(32, 32, 5);
  transpose_cast_k<<<tg5, tb, 0, stream>>>(wo, WOTb);
  cnorm_kernel<<<512, 256, 0, stream>>>(cb, CN);

  // z10: batches 0-4: WqkT_i = NT(wk_i, wq_i); batches 5-9: WVOt_i = NT(wo^T_i, wv_i)
  gX(stream, 1, WKb, WQb, nullptr, WqkTb,
     1024, 1024, 1024, 1024, W, W, W, 1024, 10, 1.0f);
  // QK_i = NT(queries_i, WqkT_i)  (z=5)
  gX(stream, 1, QSb, WqkTb, nullptr, QKb,
     1024, 1024, 1024, 1024, W, W, W, 1024, 5, 1.0f);

  // Wc1 = Wvo_0 straight = transpose(WVOb_0)
  {
    dim3 tgt(32, 32, 1);
    transpose_u16_k<<<tgt, tb, 0, stream>>>(WVOb, WCb, 1024);
  }
  // chain: Wc_{i+1} = NT(Wc_i, WVOb_i), i=1..3; Wc5 = NT(Wc4, WVOb_4)  [gemm_t]
  gX(stream, 1, WCb,         WVOb + 1 * W, nullptr, WCb + 1 * W, 1024, 1024, 1024, 1024, 0, 0, 0, 1024, 1, 1.0f);
  gX(stream, 1, WCb + 1 * W, WVOb + 2 * W, nullptr, WCb + 2 * W, 1024, 1024, 1024, 1024, 0, 0, 0, 1024, 1, 1.0f);
  gX(stream, 1, WCb + 2 * W, WVOb + 3 * W, nullptr, WCb + 3 * W, 1024, 1024, 1024, 1024, 0, 0, 0, 1024, 1, 1.0f);
  gX(stream, 1, WCb + 3 * W, WVOb + 4 * W, nullptr, WC5,         1024, 1024, 1024, 1024, 0, 0, 0, 1024, 1, 1.0f);
  // QK'_{1..4} = NT(QK_i, Wc_i) (z=4);  G = NT(CB, Wc5)
  gX(stream, 1, QKb + W, WCb, nullptr, QKP,
     1024, 1024, 1024, 1024, W, W, W, 1024, 4, 1.0f);
  gX(stream, 1, CBb, WC5, nullptr, CBW,
     512, 1024, 1024, 1024, 0, 0, 0, 1024, 1, 1.0f);

  // u0 = x (straight + transposed)
  dim3 tgx(32, 32, 32);
  cast_trans_k<<<tgx, tb, 0, stream>>>(x, U, UT);

  for (int i = 0; i < 5; ++i) {
    const int S = S_in[i], KO = K_out[i];
    const u16* qk = (i == 0) ? QKb : QKP + (size_t)(i - 1) * W;

    // logits[b] = QK'_i · u[b]^T * 1/32 -> bf16
    gX(stream, 1, qk, U, nullptr, LOG,
       KO, S, 1024, 1024, 0, (long long)S * 1024, (long long)KO * S, S, 32, 0.03125f);
    // softmax -> bf16 attn
    softmax_b<<<32 * KO, 256, 0, stream>>>(LOG, ATb, S);
    // u_{i+1}[b] = attn[b]·u[b] = NT(attn, u^T)
    gX(stream, 1, ATb, UT, nullptr, U,
       KO, 1024, S, S, (long long)KO * S, (long long)1024 * S,
       (long long)KO * 1024, 1024, 32, 1.0f);
    if (i < 4) {
      dim3 tgt(32, KO / 32, 32);
      transpose_u16_k<<<tgt, tb, 0, stream>>>(U, UT, KO);
    }
  }

  // ---- VQ: DOT = NT(u5, G); argmin(||c||^2 - 2 dot); gather ----
  gX(stream, 0, U, CBW, DOT, nullptr,
     2048, 512, 1024, 1024, 0, 0, 0, 512, 1, 1.0f);
  argmin_gather_k<<<2048, 256, 0, stream>>>(DOT, CN, cb, out);
}

// Round 15
// 658.253 us; speedup vs baseline: 1.0691x; 1.0691x over previous
//
#include <hip/hip_runtime.h>

// GridDVAE: 5-stage attention pooling + VQ, MI355X gfx950.
// R15: revert to R13 (best: 662us). R14's 3-blk/CU 128^2 gemm_m regressed
// (103us vs 84us; occupancy 36% but MfmaUtil 28% — tile economics dominate).
// Router: gemm_c (256^2, 8-phase, counted vmcnt) for b256>=192; gemm_t (64^2)
// for starved grids; gemm_s (128^2, 2 blk/CU) in between.

#define MB (1024ull * 1024ull)

typedef unsigned short u16;
typedef __attribute__((ext_vector_type(4))) float f32x4;
typedef __bf16 bf16x8 __attribute__((ext_vector_type(8)));

__device__ __forceinline__ u16 f2bf(float f) {
  unsigned u = __float_as_uint(f);
  unsigned r = u + 0x7FFFu + ((u >> 16) & 1u);   // RNE
  return (u16)(r >> 16);
}
__device__ __forceinline__ float bf2f(u16 h) {
  return __uint_as_float(((unsigned)h) << 16);
}

typedef __attribute__((address_space(1))) const void GASV;
typedef __attribute__((address_space(3))) void LASV;
__device__ __forceinline__ void async16(const void* g, void* l) {
  __builtin_amdgcn_global_load_lds((GASV*)g, (LASV*)l, 16, 0, 0);
}

__device__ __forceinline__ int xcd_swz(int bid, int nwg) {
  const int q8 = nwg >> 3, r8 = nwg & 7;
  const int xcd = bid & 7, idx = bid >> 3;
  return (xcd < r8 ? xcd * (q8 + 1) : r8 * (q8 + 1) + (xcd - r8) * q8) + idx;
}

// ---------------------------------------------------------------------------
// gemm_c: 8-phase pipelined bf16 NT GEMM, BM=BN=256, BK=64, 8 waves, 512 thr,
// 128 KiB LDS, counted vmcnt(10/10/6). One barrier per phase.
// MODE 0: f32 C. 1: bf16 C.
// ---------------------------------------------------------------------------
template<int MODE>
__global__ __launch_bounds__(512, 1)
void gemm_c(const u16* __restrict__ A, const u16* __restrict__ B,
            float* __restrict__ Cf, u16* __restrict__ Cb,
            int M, int N, int KLEN, int ld,
            long long sA, long long sB, long long sC, int ldc, float alpha,
            int nxt, int nyt)
{
  __shared__ u16 lds[65536];
  const int tid  = threadIdx.x;
  const int lane = tid & 63;
  const int w    = tid >> 6;
  const int wr   = w >> 2, wc = w & 3;

  const int wg = xcd_swz((int)blockIdx.x, (int)gridDim.x);
  const int bx = wg % nxt;
  const int by = (wg / nxt) % nyt;
  const int bz = wg / (nxt * nyt);

  const int m0 = by * 256, n0 = bx * 256;
  const u16* Ab = A + (size_t)bz * sA;
  const u16* Bb = B + (size_t)bz * sB;
  const int NT = KLEN >> 6;

  f32x4 acc[8][4] = {};

  const int Rl  = tid >> 2;
  const int sgs = (tid & 3) ^ ((tid >> 3) & 3);
  int ra0 = m0 + Rl;        ra0 = ra0 < M - 1 ? ra0 : M - 1;
  int ra1 = m0 + 128 + Rl;  ra1 = ra1 < M - 1 ? ra1 : M - 1;
  int rb0 = n0 + Rl;        rb0 = rb0 < N - 1 ? rb0 : N - 1;
  int rb1 = n0 + 128 + Rl;  rb1 = rb1 < N - 1 ? rb1 : N - 1;
  const u16* gA0 = Ab + (size_t)ra0 * ld + (sgs << 3);
  const u16* gA1 = Ab + (size_t)ra1 * ld + (sgs << 3);
  const u16* gB0 = Bb + (size_t)rb0 * ld + (sgs << 3);
  const u16* gB1 = Bb + (size_t)rb1 * ld + (sgs << 3);
  const int ldst = (w << 4) * 32;

  auto stageH = [&](int mat, int buf, int kh, int tile) {
    const int tt = tile < NT ? tile : NT - 1;
    const int kc = (tt << 6) + (kh << 5);
    u16* d = &lds[(mat << 15) + (buf << 14) + (kh << 13) + ldst];
    if (mat == 0) { async16(gA0 + kc, d); async16(gA1 + kc, d + 4096); }
    else          { async16(gB0 + kc, d); async16(gB1 + kc, d + 4096); }
  };

  const int rsel = lane & 15;
  const int ksub = lane >> 4;
  const int sw   = ksub ^ ((rsel >> 1) & 3);
  const u16* ldsA = &lds[(wr * 128 + rsel) * 32 + sw * 8];
  const u16* ldsB = &lds[32768 + (wc * 64 + rsel) * 32 + sw * 8];

  auto phase = [&](int buf, int kh, int mh, bf16x8* b,
                   int smat, int sbuf, int skh, int stile, int vm) {
    bf16x8 a[4];
    if (mh == 0) {
#pragma unroll
      for (int ni = 0; ni < 4; ++ni)
        b[ni] = *(const bf16x8*)&ldsB[buf * 16384 + kh * 8192 + ni * 512];
    }
#pragma unroll
    for (int mi = 0; mi < 4; ++mi)
      a[mi] = *(const bf16x8*)&ldsA[buf * 16384 + kh * 8192 + mh * 2048 + mi * 512];
    stageH(smat, sbuf, skh, stile);
    if (vm == 10)     asm volatile("s_waitcnt vmcnt(10)" ::: "memory");
    else if (vm == 6) asm volatile("s_waitcnt vmcnt(6)" ::: "memory");
    __builtin_amdgcn_s_setprio(1);
#pragma unroll
    for (int mi = 0; mi < 4; ++mi)
#pragma unroll
      for (int ni = 0; ni < 4; ++ni)
        acc[mh * 4 + mi][ni] = __builtin_amdgcn_mfma_f32_16x16x32_bf16(
            a[mi], b[ni], acc[mh * 4 + mi][ni], 0, 0, 0);
    __builtin_amdgcn_s_setprio(0);
    __builtin_amdgcn_s_barrier();
    __builtin_amdgcn_sched_barrier(0);   // pin: nothing hoists above barrier
  };

  stageH(1, 0, 0, 0); stageH(0, 0, 0, 0); stageH(1, 0, 1, 0); stageH(0, 0, 1, 0);
  stageH(1, 1, 0, 1); stageH(0, 1, 0, 1); stageH(1, 1, 1, 1);
  asm volatile("s_waitcnt vmcnt(6)" ::: "memory");
  __builtin_amdgcn_s_barrier();
  __builtin_amdgcn_sched_barrier(0);

  const int NI = NT >> 1;
  for (int it = 0; it < NI; ++it) {
    const int t0 = it << 1, t1 = t0 + 1;
    bf16x8 b0[4], b1[4];
    phase(0, 0, 0, b0, 0, 1, 1, t1,     -1);
    phase(0, 0, 1, b0, 1, 0, 0, t0 + 2, -1);
    phase(0, 1, 0, b1, 0, 0, 0, t0 + 2, -1);
    phase(0, 1, 1, b1, 1, 0, 1, t0 + 2, 10);
    phase(1, 0, 0, b0, 0, 0, 1, t0 + 2, -1);
    phase(1, 0, 1, b0, 1, 1, 0, t1 + 2, 10);
    phase(1, 1, 0, b1, 0, 1, 0, t1 + 2, -1);
    phase(1, 1, 1, b1, 1, 1, 1, t1 + 2, 6);
  }
  asm volatile("s_waitcnt vmcnt(0)" ::: "memory");

#pragma unroll
  for (int mi = 0; mi < 8; ++mi)
#pragma unroll
    for (int ni = 0; ni < 4; ++ni)
#pragma unroll
      for (int i = 0; i < 4; ++i) {
        const int row = m0 + wr * 128 + mi * 16 + ((lane >> 4) << 2) + i;
        const int col = n0 + wc * 64 + ni * 16 + rsel;
        if (row < M && col < N) {
          const float v = acc[mi][ni][i] * alpha;
          const size_t off = (size_t)bz * sC + (size_t)row * ldc + col;
          if (MODE == 0) Cf[off] = v;
          else           Cb[off] = f2bf(v);
        }
      }
}

// ---------------------------------------------------------------------------
// gemm_s: 128x128/BK=64, 4 waves, 256 thr, 64 KiB dbuf -> 2 blocks/CU.
// ---------------------------------------------------------------------------
template<int MODE>
__global__ __launch_bounds__(256, 2)
void gemm_s(const u16* __restrict__ A, const u16* __restrict__ B,
            float* __restrict__ Cf, u16* __restrict__ Cb,
            int M, int N, int KLEN, int ld,
            long long sA, long long sB, long long sC, int ldc, float alpha,
            int nxt, int nyt)
{
  __shared__ u16 lds[32768];
  const int tid  = threadIdx.x;
  const int lane = tid & 63;
  const int w    = tid >> 6;
  const int wr   = w >> 1, wc = w & 1;

  const int wg = xcd_swz((int)blockIdx.x, (int)gridDim.x);
  const int bx = wg % nxt;
  const int by = (wg / nxt) % nyt;
  const int bz = wg / (nxt * nyt);

  const int m0 = by * 128, n0 = bx * 128;
  const u16* Ab = A + (size_t)bz * sA;
  const u16* Bb = B + (size_t)bz * sB;
  const int NT = KLEN >> 6;

  f32x4 acc[4][4] = {};

  const int Rl  = tid >> 3;
  const int sgs = (tid & 7) ^ (Rl & 7);
  const int ldst = (w << 3) * 64;

  auto stage = [&](int t, int buf) {
    const int kc = t << 6;
#pragma unroll
    for (int mat = 0; mat < 2; ++mat)
#pragma unroll
      for (int j = 0; j < 4; ++j) {
        int rg = (mat ? n0 : m0) + j * 32 + Rl;
        const int lim = (mat ? N : M) - 1;
        rg = rg < lim ? rg : lim;
        const u16* src = (mat ? Bb : Ab) + (size_t)rg * ld + kc + (sgs << 3);
        async16(src, &lds[(buf << 14) + (mat << 13) + j * 2048 + ldst]);
      }
  };

  const int rsel = lane & 15, ksub = lane >> 4;
  const int e  = rsel & 7;
  const int s0 = ((e >> 2) << 2) | (ksub ^ (e & 3));
  const int s1 = s0 ^ 4;
  const u16* ldsA0 = &lds[(wr * 64 + rsel) * 64 + s0 * 8];
  const u16* ldsA1 = &lds[(wr * 64 + rsel) * 64 + s1 * 8];
  const u16* ldsB0 = &lds[8192 + (wc * 64 + rsel) * 64 + s0 * 8];
  const u16* ldsB1 = &lds[8192 + (wc * 64 + rsel) * 64 + s1 * 8];

  stage(0, 0);
  for (int t = 0; t < NT; ++t) {
    const int buf = t & 1;
    if (t + 1 < NT) {
      stage(t + 1, buf ^ 1);
      asm volatile("s_waitcnt vmcnt(8)" ::: "memory");
    } else {
      asm volatile("s_waitcnt vmcnt(0)" ::: "memory");
    }
    __builtin_amdgcn_s_barrier();
    bf16x8 af[4][2], bf[4][2];
#pragma unroll
    for (int f = 0; f < 4; ++f) {
      af[f][0] = *(const bf16x8*)&ldsA0[buf * 16384 + f * 1024];
      af[f][1] = *(const bf16x8*)&ldsA1[buf * 16384 + f * 1024];
      bf[f][0] = *(const bf16x8*)&ldsB0[buf * 16384 + f * 1024];
      bf[f][1] = *(const bf16x8*)&ldsB1[buf * 16384 + f * 1024];
    }
    asm volatile("s_waitcnt lgkmcnt(0)" ::: "memory");
    __builtin_amdgcn_sched_barrier(0);
    __builtin_amdgcn_s_setprio(1);
#pragma unroll
    for (int mi = 0; mi < 4; ++mi)
#pragma unroll
      for (int ni = 0; ni < 4; ++ni)
#pragma unroll
        for (int kh = 0; kh < 2; ++kh)
          acc[mi][ni] = __builtin_amdgcn_mfma_f32_16x16x32_bf16(
              af[mi][kh], bf[ni][kh], acc[mi][ni], 0, 0, 0);
    __builtin_amdgcn_s_setprio(0);
    __builtin_amdgcn_s_barrier();
  }

#pragma unroll
  for (int mi = 0; mi < 4; ++mi)
#pragma unroll
    for (int ni = 0; ni < 4; ++ni)
#pragma unroll
      for (int i = 0; i < 4; ++i) {
        const int row = m0 + wr * 64 + mi * 16 + ((lane >> 4) << 2) + i;
        const int col = n0 + wc * 64 + ni * 16 + rsel;
        if (row < M && col < N) {
          const float v = acc[mi][ni][i] * alpha;
          const size_t off = (size_t)bz * sC + (size_t)row * ldc + col;
          if (MODE == 0) Cf[off] = v;
          else           Cb[off] = f2bf(v);
        }
      }
}

// ---------------------------------------------------------------------------
// gemm_t: 64x64/BK=64, 4 waves (2x2, per-wave 32x32), 256 thr, 32 KiB LDS
// dbuf -> ~4-5 blocks/CU. For grid-starved GEMMs.
// ---------------------------------------------------------------------------
template<int MODE>
__global__ __launch_bounds__(256, 4)
void gemm_t(const u16* __restrict__ A, const u16* __restrict__ B,
            float* __restrict__ Cf, u16* __restrict__ Cb,
            int M, int N, int KLEN, int ld,
            long long sA, long long sB, long long sC, int ldc, float alpha,
            int nxt, int nyt)
{
  __shared__ u16 lds[16384];   // [buf<<13 | mat<<12 | row*64 + slot*8]
  const int tid  = threadIdx.x;
  const int lane = tid & 63;
  const int w    = tid >> 6;       // 0..3
  const int wr   = w >> 1, wc = w & 1;

  const int wg = xcd_swz((int)blockIdx.x, (int)gridDim.x);
  const int bx = wg % nxt;
  const int by = (wg / nxt) % nyt;
  const int bz = wg / (nxt * nyt);

  const int m0 = by * 64, n0 = bx * 64;
  const u16* Ab = A + (size_t)bz * sA;
  const u16* Bb = B + (size_t)bz * sB;
  const int NT = KLEN >> 6;

  f32x4 acc[2][2] = {};

  const int Rl  = tid >> 3;                  // 0..31
  const int sgs = (tid & 7) ^ (Rl & 7);      // involution src slot

  auto stage = [&](int t, int buf) {
    const int kc = t << 6;
#pragma unroll
    for (int j = 0; j < 4; ++j) {
      const int mat = j >> 1, rh = j & 1;
      int rg = (mat ? n0 : m0) + rh * 32 + Rl;
      const int lim = (mat ? N : M) - 1;
      rg = rg < lim ? rg : lim;
      const u16* src = (mat ? Bb : Ab) + (size_t)rg * ld + kc + (sgs << 3);
      async16(src, &lds[(buf << 13) + (mat << 12) + (rh * 32 + w * 8) * 64]);
    }
  };

  const int rsel = lane & 15, ksub = lane >> 4;
  const int e  = rsel & 7;
  const int s0 = ((e >> 2) << 2) | (ksub ^ (e & 3));
  const int s1 = s0 ^ 4;
  const u16* lA0 = &lds[(wr * 32 + rsel) * 64 + s0 * 8];
  const u16* lA1 = &lds[(wr * 32 + rsel) * 64 + s1 * 8];
  const u16* lB0 = &lds[4096 + (wc * 32 + rsel) * 64 + s0 * 8];
  const u16* lB1 = &lds[4096 + (wc * 32 + rsel) * 64 + s1 * 8];

  stage(0, 0);
  for (int t = 0; t < NT; ++t) {
    const int buf = t & 1;
    if (t + 1 < NT) {
      stage(t + 1, buf ^ 1);
      asm volatile("s_waitcnt vmcnt(4)" ::: "memory");
    } else {
      asm volatile("s_waitcnt vmcnt(0)" ::: "memory");
    }
    __builtin_amdgcn_s_barrier();
    bf16x8 af[2][2], bg[2][2];
#pragma unroll
    for (int f = 0; f < 2; ++f) {
      af[f][0] = *(const bf16x8*)&lA0[buf * 8192 + f * 1024];
      af[f][1] = *(const bf16x8*)&lA1[buf * 8192 + f * 1024];
      bg[f][0] = *(const bf16x8*)&lB0[buf * 8192 + f * 1024];
      bg[f][1] = *(const bf16x8*)&lB1[buf * 8192 + f * 1024];
    }
    __builtin_amdgcn_s_setprio(1);
#pragma unroll
    for (int mi = 0; mi < 2; ++mi)
#pragma unroll
      for (int ni = 0; ni < 2; ++ni)
#pragma unroll
        for (int kh = 0; kh < 2; ++kh)
          acc[mi][ni] = __builtin_amdgcn_mfma_f32_16x16x32_bf16(
              af[mi][kh], bg[ni][kh], acc[mi][ni], 0, 0, 0);
    __builtin_amdgcn_s_setprio(0);
    __builtin_amdgcn_s_barrier();
  }

#pragma unroll
  for (int mi = 0; mi < 2; ++mi)
#pragma unroll
    for (int ni = 0; ni < 2; ++ni)
#pragma unroll
      for (int i = 0; i < 4; ++i) {
        const int row = m0 + wr * 32 + mi * 16 + ((lane >> 4) << 2) + i;
        const int col = n0 + wc * 32 + ni * 16 + rsel;
        if (row < M && col < N) {
          const float v = acc[mi][ni][i] * alpha;
          const size_t off = (size_t)bz * sC + (size_t)row * ldc + col;
          if (MODE == 0) Cf[off] = v;
          else           Cb[off] = f2bf(v);
        }
      }
}

// single-launch cast of qry, wq, wk, wv, cb (f32 -> bf16)
__global__ void multicast_k(const float* __restrict__ q, const float* __restrict__ wqp,
                            const float* __restrict__ wkp, const float* __restrict__ wvp,
                            const float* __restrict__ cbp,
                            u16* __restrict__ dq, u16* __restrict__ dwq,
                            u16* __restrict__ dwk, u16* __restrict__ dwv,
                            u16* __restrict__ dcb)
{
  long long i = (long long)blockIdx.x * 256 + threadIdx.x;
  const long long stride = (long long)gridDim.x * 256;
  for (; i < 5373952ll; i += stride) {
    const float* src; u16* dst; long long j;
    if (i < 1310720)      { src = q;   dst = dq;  j = i; }
    else if (i < 2621440) { src = wqp; dst = dwq; j = i - 1310720; }
    else if (i < 3932160) { src = wkp; dst = dwk; j = i - 2621440; }
    else if (i < 5242880) { src = wvp; dst = dwv; j = i - 3932160; }
    else                  { src = cbp; dst = dcb; j = i - 5242880; }
    const float4 v = *(const float4*)&src[j << 2];
    *(ushort4*)&dst[j << 2] = make_ushort4(f2bf(v.x), f2bf(v.y), f2bf(v.z), f2bf(v.w));
  }
}

// f32 [z][1024][1024] -> bf16 straight + bf16 transposed (fused)
__global__ __launch_bounds__(256)
void cast_trans_k(const float* __restrict__ in, u16* __restrict__ h,
                  u16* __restrict__ ht)
{
  __shared__ float t[32][33];
  const int z = blockIdx.z;
  const float* src = in + (size_t)z * 1048576;
  u16* dh = h  + (size_t)z * 1048576;
  u16* dt = ht + (size_t)z * 1048576;
  const int x0 = blockIdx.x * 32, y0 = blockIdx.y * 32;
  const int tx = threadIdx.x, ty = threadIdx.y;
#pragma unroll
  for (int k = 0; k < 4; ++k) {
    const float v = src[(size_t)(y0 + ty + 8 * k) * 1024 + (x0 + tx)];
    t[ty + 8 * k][tx] = v;
    dh[(size_t)(y0 + ty + 8 * k) * 1024 + (x0 + tx)] = f2bf(v);
  }
  __syncthreads();
#pragma unroll
  for (int k = 0; k < 4; ++k)
    dt[(size_t)(x0 + ty + 8 * k) * 1024 + (y0 + tx)] = f2bf(t[tx][ty + 8 * k]);
}

// f32 [z][1024][1024] -> bf16 transposed only
__global__ __launch_bounds__(256)
void transpose_cast_k(const float* __restrict__ in, u16* __restrict__ out)
{
  __shared__ float t[32][33];
  const int z = blockIdx.z;
  const float* src = in + (size_t)z * 1048576;
  u16* dst = out + (size_t)z * 1048576;
  const int x0 = blockIdx.x * 32, y0 = blockIdx.y * 32;
  const int tx = threadIdx.x, ty = threadIdx.y;
#pragma unroll
  for (int k = 0; k < 4; ++k)
    t[ty + 8 * k][tx] = src[(size_t)(y0 + ty + 8 * k) * 1024 + (x0 + tx)];
  __syncthreads();
#pragma unroll
  for (int k = 0; k < 4; ++k)
    dst[(size_t)(x0 + ty + 8 * k) * 1024 + (y0 + tx)] = f2bf(t[tx][ty + 8 * k]);
}

// bf16 [z][R][1024] -> [z][1024][R]
__global__ __launch_bounds__(256)
void transpose_u16_k(const u16* __restrict__ in, u16* __restrict__ out, int R)
{
  __shared__ u16 t[32][33];
  const size_t zi = (size_t)blockIdx.z * R * 1024;
  const size_t zo = (size_t)blockIdx.z * 1024 * R;
  const int x0 = blockIdx.x * 32, y0 = blockIdx.y * 32;
  const int tx = threadIdx.x, ty = threadIdx.y;
#pragma unroll
  for (int k = 0; k < 4; ++k)
    t[ty + 8 * k][tx] = in[zi + (size_t)(y0 + ty + 8 * k) * 1024 + (x0 + tx)];
  __syncthreads();
#pragma unroll
  for (int k = 0; k < 4; ++k)
    out[zo + (size_t)(x0 + ty + 8 * k) * R + (y0 + tx)] = t[tx][ty + 8 * k];
}

// row softmax (len S<=1024): bf16 logits in -> bf16 attn out
__global__ __launch_bounds__(256)
void softmax_b(const u16* __restrict__ lg, u16* __restrict__ at, int S)
{
  const size_t row = blockIdx.x;
  const u16* src = lg + row * S;
  const int tid = threadIdx.x;
  float v[4];
  float mx = -3.402823466e38f;
#pragma unroll
  for (int c = 0; c < 4; ++c) {
    const int j = tid + c * 256;
    v[c] = (j < S) ? bf2f(src[j]) : -3.402823466e38f;
    mx = fmaxf(mx, v[c]);
  }
#pragma unroll
  for (int o = 32; o > 0; o >>= 1) mx = fmaxf(mx, __shfl_xor(mx, o));
  __shared__ float rmx[4];
  if ((tid & 63) == 0) rmx[tid >> 6] = mx;
  __syncthreads();
  mx = fmaxf(fmaxf(rmx[0], rmx[1]), fmaxf(rmx[2], rmx[3]));
  float sum = 0.f;
#pragma unroll
  for (int c = 0; c < 4; ++c) { v[c] = expf(v[c] - mx); sum += v[c]; }
#pragma unroll
  for (int o = 32; o > 0; o >>= 1) sum += __shfl_xor(sum, o);
  __shared__ float rsm[4];
  if ((tid & 63) == 0) rsm[tid >> 6] = sum;
  __syncthreads();
  sum = rsm[0] + rsm[1] + rsm[2] + rsm[3];
  const float inv = 1.0f / sum;
  u16* dst = at + row * S;
#pragma unroll
  for (int c = 0; c < 4; ++c) {
    const int j = tid + c * 256;
    if (j < S) dst[j] = f2bf(v[c] * inv);
  }
}

// per-code squared norm
__global__ __launch_bounds__(256)
void cnorm_kernel(const float* __restrict__ cb, float* __restrict__ cn)
{
  const int c = blockIdx.x;
  const float4 v = ((const float4*)(cb + (size_t)c * 1024))[threadIdx.x];
  float s = v.x * v.x + v.y * v.y + v.z * v.z + v.w * v.w;
#pragma unroll
  for (int o = 32; o > 0; o >>= 1) s += __shfl_xor(s, o);
  __shared__ float r4[4];
  if ((threadIdx.x & 63) == 0) r4[threadIdx.x >> 6] = s;
  __syncthreads();
  if (threadIdx.x == 0) cn[c] = r4[0] + r4[1] + r4[2] + r4[3];
}

// per latent: argmin_c (cn[c] - 2*dot[lat,c]), tie -> lower c; gather code row
__global__ __launch_bounds__(256)
void argmin_gather_k(const float* __restrict__ dot, const float* __restrict__ cn,
                     const float* __restrict__ cb, float* __restrict__ out)
{
  const size_t lat = blockIdx.x;
  const int tid = threadIdx.x;
  const float* dr = dot + lat * 512;
  float best = 3.402823466e38f;
  int bi = 0;
#pragma unroll
  for (int cc = 0; cc < 2; ++cc) {
    const int c = tid + cc * 256;
    const float sc = cn[c] - 2.0f * dr[c];
    if (sc < best || (sc == best && c < bi)) { best = sc; bi = c; }
  }
  __shared__ float rb[256];
  __shared__ int   ri[256];
  rb[tid] = best; ri[tid] = bi;
  __syncthreads();
  for (int s = 128; s > 0; s >>= 1) {
    if (tid < s) {
      const float ob = rb[tid + s];
      const int oi = ri[tid + s];
      if (ob < rb[tid] || (ob == rb[tid] && oi < ri[tid])) { rb[tid] = ob; ri[tid] = oi; }
    }
    __syncthreads();
  }
  const int sel = ri[0];
  ((float4*)(out + lat * 1024))[tid] = ((const float4*)(cb + (size_t)sel * 1024))[tid];
}

__global__ void fill_kernel(float* p, float v, int n) {
  const int i = blockIdx.x * 256 + threadIdx.x;
  if (i < n) p[i] = v;
}

// ---------------------------------------------------------------------------
// mode: 0 f32, 1 bf16
static void gX(hipStream_t st, int mode,
               const u16* A, const u16* B, float* Cf, u16* Cb,
               int M, int N, int KLEN, int ld,
               long long sA, long long sB, long long sC, int ldc,
               int batch, float alpha)
{
  const int b256 = ((M + 255) / 256) * ((N + 255) / 256) * batch;
  const int b128 = ((M + 127) / 128) * ((N + 127) / 128) * batch;
  if (b256 >= 192 && (KLEN & 127) == 0) {
    const int nxt = (N + 255) / 256, nyt = (M + 255) / 256;
    dim3 grid(nxt * nyt * batch), blk(512);
    if (mode == 0)
      gemm_c<0><<<grid, blk, 0, st>>>(A, B, Cf, Cb, M, N, KLEN, ld, sA, sB, sC, ldc, alpha, nxt, nyt);
    else
      gemm_c<1><<<grid, blk, 0, st>>>(A, B, Cf, Cb, M, N, KLEN, ld, sA, sB, sC, ldc, alpha, nxt, nyt);
  } else if (b128 < 192) {
    const int nxt = (N + 63) / 64, nyt = (M + 63) / 64;
    dim3 grid(nxt * nyt * batch), blk(256);
    if (mode == 0)
      gemm_t<0><<<grid, blk, 0, st>>>(A, B, Cf, Cb, M, N, KLEN, ld, sA, sB, sC, ldc, alpha, nxt, nyt);
    else
      gemm_t<1><<<grid, blk, 0, st>>>(A, B, Cf, Cb, M, N, KLEN, ld, sA, sB, sC, ldc, alpha, nxt, nyt);
  } else {
    const int nxt = (N + 127) / 128, nyt = (M + 127) / 128;
    dim3 grid(nxt * nyt * batch), blk(256);
    if (mode == 0)
      gemm_s<0><<<grid, blk, 0, st>>>(A, B, Cf, Cb, M, N, KLEN, ld, sA, sB, sC, ldc, alpha, nxt, nyt);
    else
      gemm_s<1><<<grid, blk, 0, st>>>(A, B, Cf, Cb, M, N, KLEN, ld, sA, sB, sC, ldc, alpha, nxt, nyt);
  }
}

extern "C" void kernel_launch(void* const* d_in, const int* in_sizes, int n_in,
                              void* d_out, int out_size, void* d_ws, size_t ws_size,
                              hipStream_t stream)
{
  const float* x   = (const float*)d_in[0];
  const float* qry = (const float*)d_in[1];
  const float* wq  = (const float*)d_in[2];
  const float* wk  = (const float*)d_in[3];
  const float* wv  = (const float*)d_in[4];
  const float* wo  = (const float*)d_in[5];
  const float* cb  = (const float*)d_in[6];
  float* out = (float*)d_out;

  const size_t NEED = 312 * MB;
  if (ws_size < NEED) {
    fill_kernel<<<(out_size + 255) / 256, 256, 0, stream>>>(out, (float)ws_size, out_size);
    return;
  }
  char* ws = (char*)d_ws;
  const long long W = 1048576;  // 1024*1024 elements
  // persistent
  u16*  QKb   = (u16*)(ws + 0 * MB);    // [5W] QK_i = Q·wq·wk^T
  u16*  WqkTb = (u16*)(ws + 10 * MB);   // [5W] z10 C batches 0-4
  u16*  WVOb  = (u16*)(ws + 20 * MB);   // [5W] z10 C batches 5-9: (Wv·Wo)^T
  u16*  CBb   = (u16*)(ws + 30 * MB);   // [512,1024]
  float* CN   = (float*)(ws + 31 * MB); // [512]
  u16*  QKP   = (u16*)(ws + 32 * MB);   // [4W] QK'_i
  u16*  WCb   = (u16*)(ws + 40 * MB);   // [4W] Wc1..Wc4
  u16*  WC5   = (u16*)(ws + 48 * MB);   // [W]
  u16*  CBW   = (u16*)(ws + 50 * MB);   // G = NT(CB, Wc5)
  float* DOT  = (float*)(ws + 51 * MB); // [2048,512]
  // transient
  u16*  U    = (u16*)(ws + 56 * MB);    // u_i [32][S,1024]
  u16*  UT   = (u16*)(ws + 120 * MB);   // u^T [32][1024,S]
  u16*  ATb  = (u16*)(ws + 184 * MB);   // attn [32][KO,S]
  u16*  LOG  = (u16*)(ws + 248 * MB);   // logits bf16
  // setup transients (overlay U/UT, dead before cast_trans)
  u16*  QSb  = (u16*)(ws + 56 * MB);    // queries [5W]
  u16*  WQb  = (u16*)(ws + 66 * MB);    // B-group batches 0-4
  u16*  WVb  = (u16*)(ws + 76 * MB);    // B-group batches 5-9
  u16*  WKb  = (u16*)(ws + 86 * MB);    // A-group batches 0-4
  u16*  WOTb = (u16*)(ws + 96 * MB);    // A-group batches 5-9

  const int S_in[5]  = {1024, 1024, 512, 256, 128};
  const int K_out[5] = {1024, 512, 256, 128, 64};

  // ---- setup ----
  multicast_k<<<2048, 256, 0, stream>>>(qry, wq, wk, wv, cb,
                                        QSb, WQb, WKb, WVb, CBb);
  dim3 tb(32, 8), tg5(32, 32, 5);
  transpose_cast_k<<<tg5, tb, 0, stream>>>(wo, WOTb);
  cnorm_kernel<<<512, 256, 0, stream>>>(cb, CN);

  // z10: batches 0-4: WqkT_i = NT(wk_i, wq_i); batches 5-9: WVOt_i = NT(wo^T_i, wv_i)
  gX(stream, 1, WKb, WQb, nullptr, WqkTb,
     1024, 1024, 1024, 1024, W, W, W, 1024, 10, 1.0f);
  // QK_i = NT(queries_i, WqkT_i)  (z=5)
  gX(stream, 1, QSb, WqkTb, nullptr, QKb,
     1024, 1024, 1024, 1024, W, W, W, 1024, 5, 1.0f);

  // Wc1 = Wvo_0 straight = transpose(WVOb_0)
  {
    dim3 tgt(32, 32, 1);
    transpose_u16_k<<<tgt, tb, 0, stream>>>(WVOb, WCb, 1024);
  }
  // chain: Wc_{i+1} = NT(Wc_i, WVOb_i), i=1..3; Wc5 = NT(Wc4, WVOb_4)  [gemm_t]
  gX(stream, 1, WCb,         WVOb + 1 * W, nullptr, WCb + 1 * W, 1024, 1024, 1024, 1024, 0, 0, 0, 1024, 1, 1.0f);
  gX(stream, 1, WCb + 1 * W, WVOb + 2 * W, nullptr, WCb + 2 * W, 1024, 1024, 1024, 1024, 0, 0, 0, 1024, 1, 1.0f);
  gX(stream, 1, WCb + 2 * W, WVOb + 3 * W, nullptr, WCb + 3 * W, 1024, 1024, 1024, 1024, 0, 0, 0, 1024, 1, 1.0f);
  gX(stream, 1, WCb + 3 * W, WVOb + 4 * W, nullptr, WC5,         1024, 1024, 1024, 1024, 0, 0, 0, 1024, 1, 1.0f);
  // QK'_{1..4} = NT(QK_i, Wc_i) (z=4);  G = NT(CB, Wc5)
  gX(stream, 1, QKb + W, WCb, nullptr, QKP,
     1024, 1024, 1024, 1024, W, W, W, 1024, 4, 1.0f);
  gX(stream, 1, CBb, WC5, nullptr, CBW,
     512, 1024, 1024, 1024, 0, 0, 0, 1024, 1, 1.0f);

  // u0 = x (straight + transposed)
  dim3 tgx(32, 32, 32);
  cast_trans_k<<<tgx, tb, 0, stream>>>(x, U, UT);

  for (int i = 0; i < 5; ++i) {
    const int S = S_in[i], KO = K_out[i];
    const u16* qk = (i == 0) ? QKb : QKP + (size_t)(i - 1) * W;

    // logits[b] = QK'_i · u[b]^T * 1/32 -> bf16
    gX(stream, 1, qk, U, nullptr, LOG,
       KO, S, 1024, 1024, 0, (long long)S * 1024, (long long)KO * S, S, 32, 0.03125f);
    // softmax -> bf16 attn
    softmax_b<<<32 * KO, 256, 0, stream>>>(LOG, ATb, S);
    // u_{i+1}[b] = attn[b]·u[b] = NT(attn, u^T)
    gX(stream, 1, ATb, UT, nullptr, U,
       KO, 1024, S, S, (long long)KO * S, (long long)1024 * S,
       (long long)KO * 1024, 1024, 32, 1.0f);
    if (i < 4) {
      dim3 tgt(32, KO / 32, 32);
      transpose_u16_k<<<tgt, tb, 0, stream>>>(U, UT, KO);
    }
  }

  // ---- VQ: DOT = NT(u5, G); argmin(||c||^2 - 2 dot); gather ----
  gX(stream, 0, U, CBW, DOT, nullptr,
     2048, 512, 1024, 1024, 0, 0, 0, 512, 1, 1.0f);
  argmin_gather_k<<<2048, 256, 0, stream>>>(DOT, CN, cb, out);
}